// Round 3
// baseline (295.775 us; speedup 1.0000x reference)
//
#include <hip/hip_runtime.h>
#include <hip/hip_fp16.h>
#include <stdint.h>

// Problem constants (B=8, N=2048, F=512, A=512)
#define B_   8
#define N_   2048
#define F_   512
#define A_   512
#define MTOT (B_ * N_)   // 16384 rows total

typedef unsigned short u16;
typedef unsigned int   u32;
typedef __attribute__((ext_vector_type(8))) __bf16    bf16x8;
typedef __attribute__((ext_vector_type(8))) _Float16  f16x8;
typedef __attribute__((ext_vector_type(4))) float     f32x4;

// ---------- scalar converts ----------
__device__ __forceinline__ u16 f2bf(float f) {   // RNE
    u32 u = __builtin_bit_cast(u32, f);
    u32 r = u + 0x7fffu + ((u >> 16) & 1u);
    return (u16)(r >> 16);
}
__device__ __forceinline__ u16 f2h(float f) {    // RNE via HW cvt
    _Float16 h = (_Float16)f;
    return __builtin_bit_cast(u16, h);
}

// async global->LDS, 16B per lane
__device__ __forceinline__ void gload_lds16(const u16* g, u16* l) {
    __builtin_amdgcn_global_load_lds(
        (const __attribute__((address_space(1))) u32*)(const u32*)g,
        (__attribute__((address_space(3))) u32*)(u32*)l,
        16, 0, 0);
}

// ---------- fp32 -> {bf16|fp16} convert (4 elems/thread) ----------
template <int FMT>   // 0 = bf16, 1 = fp16
__global__ __launch_bounds__(256) void cvt16(const float* __restrict__ in,
                                             u16* __restrict__ out, int n4) {
    int i = blockIdx.x * 256 + threadIdx.x;
    if (i >= n4) return;
    float4 v = ((const float4*)in)[i];
    u32 a, b;
    if constexpr (FMT == 0) {
        a = (u32)f2bf(v.x) | ((u32)f2bf(v.y) << 16);
        b = (u32)f2bf(v.z) | ((u32)f2bf(v.w) << 16);
    } else {
        a = (u32)f2h(v.x) | ((u32)f2h(v.y) << 16);
        b = (u32)f2h(v.z) | ((u32)f2h(v.w) << 16);
    }
    ((uint2*)out)[i] = make_uint2(a, b);
}

// ---------- NT GEMM: C[m][n] = sum_k A[m][k] * B[n][k] (+bias) ----------
// BIAS_MODE: 0 none, 1 bias[n] (col), 2 bias[m] (row).
// OUT_FMT: 0 = bf16, 1 = fp32, 2 = fp16
// IN_FMT:  0 = bf16 MFMA, 1 = fp16 MFMA
// 128x128 tile, BK=64, 256 threads (4 waves 2x2), 4x4 16x16x32 frags/wave.
template <int BIAS_MODE, int OUT_FMT, int IN_FMT>
__global__ __launch_bounds__(256)
void gemm_nt(const u16* __restrict__ A, int lda, long sA,
             const u16* __restrict__ Bm, int ldb, long sB,
             const float* __restrict__ bias,
             void* __restrict__ Cv, int ldc, long sC, int K)
{
    __shared__ alignas(16) u16 lA[128 * 64];
    __shared__ alignas(16) u16 lB[128 * 64];

    const int z = blockIdx.z;
    A  += (long)z * sA;
    Bm += (long)z * sB;

    const int m0 = blockIdx.x * 128;
    const int n0 = blockIdx.y * 128;
    const int t = threadIdx.x;
    const int lane = t & 63, wave = t >> 6;
    const int wr = (wave >> 1) * 64;
    const int wc = (wave & 1) * 64;
    const int frow = lane & 15;
    const int fk   = (lane >> 4) * 8;

    f32x4 acc[4][4];
#pragma unroll
    for (int i = 0; i < 4; i++)
#pragma unroll
        for (int j = 0; j < 4; j++)
#pragma unroll
            for (int r = 0; r < 4; r++) acc[i][j][r] = 0.f;

    const int srow = t >> 3;
    const int scol = (t & 7) * 8;

    for (int kt = 0; kt < K; kt += 64) {
        __syncthreads();
#pragma unroll
        for (int s = 0; s < 4; ++s) {
            int row = s * 32 + srow;
            const u16* ga = A  + (long)(m0 + row) * lda + (kt + scol);
            const u16* gb = Bm + (long)(n0 + row) * ldb + (kt + scol);
            gload_lds16(ga, &lA[s * 2048 + t * 8]);
            gload_lds16(gb, &lB[s * 2048 + t * 8]);
        }
        __syncthreads();
#pragma unroll
        for (int kk = 0; kk < 64; kk += 32) {
            uint4 ar[4], br[4];
#pragma unroll
            for (int i = 0; i < 4; i++)
                ar[i] = *(const uint4*)&lA[(wr + i * 16 + frow) * 64 + kk + fk];
#pragma unroll
            for (int j = 0; j < 4; j++)
                br[j] = *(const uint4*)&lB[(wc + j * 16 + frow) * 64 + kk + fk];
#pragma unroll
            for (int i = 0; i < 4; i++)
#pragma unroll
                for (int j = 0; j < 4; j++) {
                    if constexpr (IN_FMT == 0)
                        acc[i][j] = __builtin_amdgcn_mfma_f32_16x16x32_bf16(
                            __builtin_bit_cast(bf16x8, ar[i]),
                            __builtin_bit_cast(bf16x8, br[j]),
                            acc[i][j], 0, 0, 0);
                    else
                        acc[i][j] = __builtin_amdgcn_mfma_f32_16x16x32_f16(
                            __builtin_bit_cast(f16x8, ar[i]),
                            __builtin_bit_cast(f16x8, br[j]),
                            acc[i][j], 0, 0, 0);
                }
        }
    }

    // epilogue: C/D layout col = lane&15, row = (lane>>4)*4 + r
    const int rbase = (lane >> 4) * 4;
#pragma unroll
    for (int i = 0; i < 4; i++) {
        int m = m0 + wr + i * 16 + rbase;
#pragma unroll
        for (int j = 0; j < 4; j++) {
            int n = n0 + wc + j * 16 + frow;
            float badd = 0.f;
            if (BIAS_MODE == 1) badd = bias[n];
#pragma unroll
            for (int r = 0; r < 4; r++) {
                float v = acc[i][j][r];
                if (BIAS_MODE == 1) v += badd;
                if (BIAS_MODE == 2) v += bias[m + r];
                long idx = (long)(m + r) * ldc + n + (long)z * sC;
                if constexpr (OUT_FMT == 0) {
                    ((u16*)Cv)[idx] = f2bf(v);
                } else if constexpr (OUT_FMT == 1) {
                    ((float*)Cv)[idx] = v;
                } else {
                    ((u16*)Cv)[idx] = f2h(v);
                }
            }
        }
    }
}

// ---------- row softmax: fp32 scores in, bf16 weights out (in place) ----------
// Row region is 2048 fp32 (8192 B); bf16 P written into first 4096 B.
__global__ __launch_bounds__(256) void softmax_rows(float* __restrict__ S) {
    __shared__ float red[16];
    const long row = blockIdx.x;
    float* p = S + row * (long)N_;
    const int t = threadIdx.x;
    const int lane = t & 63, wave = t >> 6;

    float4 r0 = ((const float4*)p)[2 * t];
    float4 r1 = ((const float4*)p)[2 * t + 1];
    float v[8] = {r0.x, r0.y, r0.z, r0.w, r1.x, r1.y, r1.z, r1.w};

    float mx = v[0];
#pragma unroll
    for (int j = 1; j < 8; j++) mx = fmaxf(mx, v[j]);
#pragma unroll
    for (int o = 32; o; o >>= 1) mx = fmaxf(mx, __shfl_xor(mx, o));
    if (lane == 0) red[wave] = mx;
    __syncthreads();
    mx = fmaxf(fmaxf(red[0], red[1]), fmaxf(red[2], red[3]));

    float s = 0.f;
#pragma unroll
    for (int j = 0; j < 8; j++) { v[j] = __expf(v[j] - mx); s += v[j]; }
#pragma unroll
    for (int o = 32; o; o >>= 1) s += __shfl_xor(s, o);
    if (lane == 0) red[8 + wave] = s;
    __syncthreads();
    s = red[8] + red[9] + red[10] + red[11];
    float inv = 1.f / s;
    u32 w[4];
#pragma unroll
    for (int j = 0; j < 4; j++) {
        u32 lo = f2bf(v[2 * j] * inv);
        u32 hi = f2bf(v[2 * j + 1] * inv);
        w[j] = lo | (hi << 16);
    }
    ((uint4*)(u16*)p)[t] = make_uint4(w[0], w[1], w[2], w[3]);
}

// ---------- BN stats: per n over (b,f): 4096 values -> mean, rstd ----------
__global__ __launch_bounds__(256) void bn_stats(const float* __restrict__ lin,
                                                float* __restrict__ stats) {
    __shared__ float red[16];
    const int n = blockIdx.x;
    const int t = threadIdx.x;
    const int lane = t & 63, wave = t >> 6;
    float s = 0.f, s2 = 0.f;
    for (int idx = t; idx < 1024; idx += 256) {
        int b = idx >> 7, f4 = idx & 127;
        float4 x = ((const float4*)(lin + ((long)b * N_ + n) * F_))[f4];
        s  += x.x + x.y + x.z + x.w;
        s2 += x.x * x.x + x.y * x.y + x.z * x.z + x.w * x.w;
    }
#pragma unroll
    for (int o = 32; o; o >>= 1) { s += __shfl_xor(s, o); s2 += __shfl_xor(s2, o); }
    if (lane == 0) { red[wave] = s; red[8 + wave] = s2; }
    __syncthreads();
    if (t == 0) {
        float S1 = red[0] + red[1] + red[2] + red[3];
        float S2 = red[8] + red[9] + red[10] + red[11];
        float mean = S1 / 4096.f;
        float var  = S2 / 4096.f - mean * mean;
        stats[n]      = mean;
        stats[N_ + n] = rsqrtf(var + 1e-5f);
    }
}

// ---------- BN apply + ReLU + residual ----------
__global__ __launch_bounds__(256)
void bn_relu_add(const float* __restrict__ lin, const float* __restrict__ x,
                 const float* __restrict__ gamma, const float* __restrict__ beta,
                 const float* __restrict__ stats, float* __restrict__ out) {
    long i4 = (long)blockIdx.x * 256 + threadIdx.x;
    int n = (int)((i4 >> 7) & (N_ - 1));
    float mean = stats[n], rstd = stats[N_ + n];
    float scale = gamma[n] * rstd;
    float shift = beta[n] - mean * scale;
    float4 l  = ((const float4*)lin)[i4];
    float4 xx = ((const float4*)x)[i4];
    float4 o;
    o.x = fmaxf(l.x * scale + shift, 0.f) + xx.x;
    o.y = fmaxf(l.y * scale + shift, 0.f) + xx.y;
    o.z = fmaxf(l.z * scale + shift, 0.f) + xx.z;
    o.w = fmaxf(l.w * scale + shift, 0.f) + xx.w;
    ((float4*)out)[i4] = o;
}

extern "C" void kernel_launch(void* const* d_in, const int* in_sizes, int n_in,
                              void* d_out, int out_size, void* d_ws, size_t ws_size,
                              hipStream_t stream)
{
    (void)in_sizes; (void)n_in; (void)out_size; (void)ws_size;
    const float* x     = (const float*)d_in[0];
    const float* Wq    = (const float*)d_in[1];
    const float* bq    = (const float*)d_in[2];
    const float* Wk    = (const float*)d_in[3];
    const float* bk    = (const float*)d_in[4];
    const float* Wv    = (const float*)d_in[5];
    const float* bv    = (const float*)d_in[6];
    const float* Wo    = (const float*)d_in[7];
    const float* bo    = (const float*)d_in[8];
    const float* gamma = (const float*)d_in[9];
    const float* beta  = (const float*)d_in[10];
    float* out = (float*)d_out;
    char*  ws  = (char*)d_ws;

    const size_t MB = 1024 * 1024;
    // ws layout (180 MB total, same proven footprint as round 2)
    u16*   wqh   = (u16*)(ws + 0);                 // fp16 [512][512]
    u16*   wkh   = (u16*)(ws + 512 * 1024);        // fp16
    u16*   wvh   = (u16*)(ws + 1 * MB);            // fp16
    u16*   wob   = (u16*)(ws + 1 * MB + 512 * 1024); // bf16
    float* stats = (float*)(ws + 2 * MB);          // 16 KB
    u16*   xh    = (u16*)(ws + 4 * MB);            // 16 MB fp16 [16384][512]
    u16*   qh    = (u16*)(ws + 20 * MB);           // 16 MB fp16
    u16*   kh    = (u16*)(ws + 36 * MB);           // 16 MB fp16
    u16*   vt    = (u16*)(ws + 52 * MB);           // 16 MB bf16 [512][16384] (V^T)
    float* Sf    = (float*)(ws + 68 * MB);         // 64 MB fp32 scores (4 batches/chunk)
    u16*   feat  = (u16*)(ws + 132 * MB);          // 16 MB bf16
    float* lin   = (float*)(ws + 148 * MB);        // 32 MB fp32

    // converts: x/Wq/Wk/Wv -> fp16; Wo -> bf16
    cvt16<1><<<8192, 256, 0, stream>>>(x,  xh,  2097152);
    cvt16<1><<<256,  256, 0, stream>>>(Wq, wqh, 65536);
    cvt16<1><<<256,  256, 0, stream>>>(Wk, wkh, 65536);
    cvt16<1><<<256,  256, 0, stream>>>(Wv, wvh, 65536);
    cvt16<0><<<256,  256, 0, stream>>>(Wo, wob, 65536);

    // q = x @ Wq^T + bq  (fp16 MFMA -> fp16 out)
    gemm_nt<1, 2, 1><<<dim3(128, 4, 1), 256, 0, stream>>>(
        xh, 512, 0, wqh, 512, 0, bq, qh, 512, 0, 512);
    // k = x @ Wk^T + bk
    gemm_nt<1, 2, 1><<<dim3(128, 4, 1), 256, 0, stream>>>(
        xh, 512, 0, wkh, 512, 0, bk, kh, 512, 0, 512);
    // v^T = Wv @ x^T + bv(row)  (fp16 MFMA -> bf16 out)  vt[a][m_global]
    gemm_nt<2, 0, 1><<<dim3(4, 128, 1), 256, 0, stream>>>(
        wvh, 512, 0, xh, 512, 0, bv, vt, MTOT, 0, 512);

    // attention in 2 chunks of 4 batches (S buffer reused)
    for (int c = 0; c < 2; ++c) {
        const u16* qc = qh + (long)c * 4 * N_ * A_;
        const u16* kc = kh + (long)c * 4 * N_ * A_;
        // S = q @ k^T  (fp16 MFMA -> fp32 out)
        gemm_nt<0, 1, 1><<<dim3(16, 16, 4), 256, 0, stream>>>(
            qc, 512, (long)N_ * A_, kc, 512, (long)N_ * A_, nullptr,
            Sf, N_, (long)N_ * N_, 512);
        // softmax in place: fp32 -> bf16 P (row stride becomes 4096 u16)
        softmax_rows<<<4 * N_, 256, 0, stream>>>(Sf);
        // feat = P @ v  (bf16 MFMA; P ld=4096, batch stride 2048*4096 u16)
        gemm_nt<0, 0, 0><<<dim3(16, 4, 4), 256, 0, stream>>>(
            (const u16*)Sf, 2 * N_, (long)N_ * 2 * N_,
            vt + (long)c * 4 * N_, MTOT, N_, nullptr,
            feat + (long)c * 4 * N_ * A_, A_, (long)N_ * A_, 2048);
    }

    // lin = feat @ Wo^T + bo  (bf16 MFMA -> fp32)
    gemm_nt<1, 1, 0><<<dim3(128, 4, 1), 256, 0, stream>>>(
        feat, 512, 0, wob, 512, 0, bo, lin, 512, 0, 512);
    // BN stats per n, then BN+ReLU+residual
    bn_stats<<<2048, 256, 0, stream>>>(lin, stats);
    bn_relu_add<<<8192, 256, 0, stream>>>(lin, x, gamma, beta, stats, out);
}

// Round 4
// 245.573 us; speedup vs baseline: 1.2044x; 1.2044x over previous
//
#include <hip/hip_runtime.h>
#include <hip/hip_fp16.h>
#include <stdint.h>

// Problem constants (B=8, N=2048, F=512, A=512)
#define B_   8
#define N_   2048
#define F_   512
#define A_   512
#define MTOT (B_ * N_)   // 16384 rows total

typedef unsigned short u16;
typedef unsigned int   u32;
typedef __attribute__((ext_vector_type(8))) __bf16    bf16x8;
typedef __attribute__((ext_vector_type(8))) _Float16  f16x8;
typedef __attribute__((ext_vector_type(4))) float     f32x4;

// ---------- scalar converts ----------
__device__ __forceinline__ u16 f2bf(float f) {   // RNE
    u32 u = __builtin_bit_cast(u32, f);
    u32 r = u + 0x7fffu + ((u >> 16) & 1u);
    return (u16)(r >> 16);
}
__device__ __forceinline__ u16 f2h(float f) {    // RNE via HW cvt
    _Float16 h = (_Float16)f;
    return __builtin_bit_cast(u16, h);
}

// async global->LDS, 16B per lane
__device__ __forceinline__ void gload_lds16(const u16* g, u16* l) {
    __builtin_amdgcn_global_load_lds(
        (const __attribute__((address_space(1))) u32*)(const u32*)g,
        (__attribute__((address_space(3))) u32*)(u32*)l,
        16, 0, 0);
}

// ---------- fp32 -> {bf16|fp16} convert (4 elems/thread) ----------
template <int FMT>   // 0 = bf16, 1 = fp16
__global__ __launch_bounds__(256) void cvt16(const float* __restrict__ in,
                                             u16* __restrict__ out, int n4) {
    int i = blockIdx.x * 256 + threadIdx.x;
    if (i >= n4) return;
    float4 v = ((const float4*)in)[i];
    u32 a, b;
    if constexpr (FMT == 0) {
        a = (u32)f2bf(v.x) | ((u32)f2bf(v.y) << 16);
        b = (u32)f2bf(v.z) | ((u32)f2bf(v.w) << 16);
    } else {
        a = (u32)f2h(v.x) | ((u32)f2h(v.y) << 16);
        b = (u32)f2h(v.z) | ((u32)f2h(v.w) << 16);
    }
    ((uint2*)out)[i] = make_uint2(a, b);
}

// ---------- NT GEMM: C[m][n] = sum_k A[m][k] * B[n][k] (+bias) ----------
// BIAS_MODE: 0 none, 1 bias[n] (col), 2 bias[m] (row).
// OUT_FMT: 0 = bf16, 1 = fp32, 2 = fp16
// IN_FMT:  0 = bf16 MFMA, 1 = fp16 MFMA
// 128x128 tile, BK=64, 256 threads (4 waves 2x2), 4x4 16x16x32 frags/wave.
template <int BIAS_MODE, int OUT_FMT, int IN_FMT>
__global__ __launch_bounds__(256)
void gemm_nt(const u16* __restrict__ A, int lda, long sA,
             const u16* __restrict__ Bm, int ldb, long sB,
             const float* __restrict__ bias,
             void* __restrict__ Cv, int ldc, long sC, int K)
{
    __shared__ alignas(16) u16 lA[128 * 64];
    __shared__ alignas(16) u16 lB[128 * 64];

    const int z = blockIdx.z;
    A  += (long)z * sA;
    Bm += (long)z * sB;

    const int m0 = blockIdx.x * 128;
    const int n0 = blockIdx.y * 128;
    const int t = threadIdx.x;
    const int lane = t & 63, wave = t >> 6;
    const int wr = (wave >> 1) * 64;
    const int wc = (wave & 1) * 64;
    const int frow = lane & 15;
    const int fk   = (lane >> 4) * 8;

    f32x4 acc[4][4];
#pragma unroll
    for (int i = 0; i < 4; i++)
#pragma unroll
        for (int j = 0; j < 4; j++)
#pragma unroll
            for (int r = 0; r < 4; r++) acc[i][j][r] = 0.f;

    const int srow = t >> 3;
    const int scol = (t & 7) * 8;

    for (int kt = 0; kt < K; kt += 64) {
        __syncthreads();
#pragma unroll
        for (int s = 0; s < 4; ++s) {
            int row = s * 32 + srow;
            const u16* ga = A  + (long)(m0 + row) * lda + (kt + scol);
            const u16* gb = Bm + (long)(n0 + row) * ldb + (kt + scol);
            gload_lds16(ga, &lA[s * 2048 + t * 8]);
            gload_lds16(gb, &lB[s * 2048 + t * 8]);
        }
        __syncthreads();
#pragma unroll
        for (int kk = 0; kk < 64; kk += 32) {
            uint4 ar[4], br[4];
#pragma unroll
            for (int i = 0; i < 4; i++)
                ar[i] = *(const uint4*)&lA[(wr + i * 16 + frow) * 64 + kk + fk];
#pragma unroll
            for (int j = 0; j < 4; j++)
                br[j] = *(const uint4*)&lB[(wc + j * 16 + frow) * 64 + kk + fk];
#pragma unroll
            for (int i = 0; i < 4; i++)
#pragma unroll
                for (int j = 0; j < 4; j++) {
                    if constexpr (IN_FMT == 0)
                        acc[i][j] = __builtin_amdgcn_mfma_f32_16x16x32_bf16(
                            __builtin_bit_cast(bf16x8, ar[i]),
                            __builtin_bit_cast(bf16x8, br[j]),
                            acc[i][j], 0, 0, 0);
                    else
                        acc[i][j] = __builtin_amdgcn_mfma_f32_16x16x32_f16(
                            __builtin_bit_cast(f16x8, ar[i]),
                            __builtin_bit_cast(f16x8, br[j]),
                            acc[i][j], 0, 0, 0);
                }
        }
    }

    // epilogue: C/D layout col = lane&15, row = (lane>>4)*4 + r
    const int rbase = (lane >> 4) * 4;
#pragma unroll
    for (int i = 0; i < 4; i++) {
        int m = m0 + wr + i * 16 + rbase;
#pragma unroll
        for (int j = 0; j < 4; j++) {
            int n = n0 + wc + j * 16 + frow;
            float badd = 0.f;
            if (BIAS_MODE == 1) badd = bias[n];
#pragma unroll
            for (int r = 0; r < 4; r++) {
                float v = acc[i][j][r];
                if (BIAS_MODE == 1) v += badd;
                if (BIAS_MODE == 2) v += bias[m + r];
                long idx = (long)(m + r) * ldc + n + (long)z * sC;
                if constexpr (OUT_FMT == 0) {
                    ((u16*)Cv)[idx] = f2bf(v);
                } else if constexpr (OUT_FMT == 1) {
                    ((float*)Cv)[idx] = v;
                } else {
                    ((u16*)Cv)[idx] = f2h(v);
                }
            }
        }
    }
}

// ---------- row softmax: fp16 scores in, bf16 weights out, in place ----------
// Row = 2048 fp16 (4096 B) -> 2048 bf16 (4096 B), same bytes.
__global__ __launch_bounds__(256) void softmax_rows(u16* __restrict__ S) {
    __shared__ float red[16];
    const long row = blockIdx.x;
    u16* p = S + row * (long)N_;
    const int t = threadIdx.x;
    const int lane = t & 63, wave = t >> 6;

    uint4 raw = ((const uint4*)p)[t];   // 8 fp16 per thread
    const __half2* hp = (const __half2*)&raw;
    float v[8];
#pragma unroll
    for (int j = 0; j < 4; j++) {
        float2 f = __half22float2(hp[j]);
        v[2 * j]     = f.x;
        v[2 * j + 1] = f.y;
    }
    float mx = v[0];
#pragma unroll
    for (int j = 1; j < 8; j++) mx = fmaxf(mx, v[j]);
#pragma unroll
    for (int o = 32; o; o >>= 1) mx = fmaxf(mx, __shfl_xor(mx, o));
    if (lane == 0) red[wave] = mx;
    __syncthreads();
    mx = fmaxf(fmaxf(red[0], red[1]), fmaxf(red[2], red[3]));

    float s = 0.f;
#pragma unroll
    for (int j = 0; j < 8; j++) { v[j] = __expf(v[j] - mx); s += v[j]; }
#pragma unroll
    for (int o = 32; o; o >>= 1) s += __shfl_xor(s, o);
    if (lane == 0) red[8 + wave] = s;
    __syncthreads();
    s = red[8] + red[9] + red[10] + red[11];
    float inv = 1.f / s;
    u32 w[4];
#pragma unroll
    for (int j = 0; j < 4; j++) {
        u32 lo = f2bf(v[2 * j] * inv);
        u32 hi = f2bf(v[2 * j + 1] * inv);
        w[j] = lo | (hi << 16);
    }
    ((uint4*)p)[t] = make_uint4(w[0], w[1], w[2], w[3]);
}

// ---------- BN stats: per n over (b,f): 4096 values -> mean, rstd ----------
__global__ __launch_bounds__(256) void bn_stats(const float* __restrict__ lin,
                                                float* __restrict__ stats) {
    __shared__ float red[16];
    const int n = blockIdx.x;
    const int t = threadIdx.x;
    const int lane = t & 63, wave = t >> 6;
    float s = 0.f, s2 = 0.f;
    for (int idx = t; idx < 1024; idx += 256) {
        int b = idx >> 7, f4 = idx & 127;
        float4 x = ((const float4*)(lin + ((long)b * N_ + n) * F_))[f4];
        s  += x.x + x.y + x.z + x.w;
        s2 += x.x * x.x + x.y * x.y + x.z * x.z + x.w * x.w;
    }
#pragma unroll
    for (int o = 32; o; o >>= 1) { s += __shfl_xor(s, o); s2 += __shfl_xor(s2, o); }
    if (lane == 0) { red[wave] = s; red[8 + wave] = s2; }
    __syncthreads();
    if (t == 0) {
        float S1 = red[0] + red[1] + red[2] + red[3];
        float S2 = red[8] + red[9] + red[10] + red[11];
        float mean = S1 / 4096.f;
        float var  = S2 / 4096.f - mean * mean;
        stats[n]      = mean;
        stats[N_ + n] = rsqrtf(var + 1e-5f);
    }
}

// ---------- BN apply + ReLU + residual ----------
__global__ __launch_bounds__(256)
void bn_relu_add(const float* __restrict__ lin, const float* __restrict__ x,
                 const float* __restrict__ gamma, const float* __restrict__ beta,
                 const float* __restrict__ stats, float* __restrict__ out) {
    long i4 = (long)blockIdx.x * 256 + threadIdx.x;
    int n = (int)((i4 >> 7) & (N_ - 1));
    float mean = stats[n], rstd = stats[N_ + n];
    float scale = gamma[n] * rstd;
    float shift = beta[n] - mean * scale;
    float4 l  = ((const float4*)lin)[i4];
    float4 xx = ((const float4*)x)[i4];
    float4 o;
    o.x = fmaxf(l.x * scale + shift, 0.f) + xx.x;
    o.y = fmaxf(l.y * scale + shift, 0.f) + xx.y;
    o.z = fmaxf(l.z * scale + shift, 0.f) + xx.z;
    o.w = fmaxf(l.w * scale + shift, 0.f) + xx.w;
    ((float4*)out)[i4] = o;
}

extern "C" void kernel_launch(void* const* d_in, const int* in_sizes, int n_in,
                              void* d_out, int out_size, void* d_ws, size_t ws_size,
                              hipStream_t stream)
{
    (void)in_sizes; (void)n_in; (void)out_size; (void)ws_size;
    const float* x     = (const float*)d_in[0];
    const float* Wq    = (const float*)d_in[1];
    const float* bq    = (const float*)d_in[2];
    const float* Wk    = (const float*)d_in[3];
    const float* bk    = (const float*)d_in[4];
    const float* Wv    = (const float*)d_in[5];
    const float* bv    = (const float*)d_in[6];
    const float* Wo    = (const float*)d_in[7];
    const float* bo    = (const float*)d_in[8];
    const float* gamma = (const float*)d_in[9];
    const float* beta  = (const float*)d_in[10];
    float* out = (float*)d_out;
    char*  ws  = (char*)d_ws;

    const size_t MB = 1024 * 1024;
    // ws layout (180 MB total, same proven footprint)
    u16*   wqkh  = (u16*)(ws + 0);                 // fp16 [1024][512]: rows 0-511 Wq, 512-1023 Wk
    u16*   wvh   = (u16*)(ws + 1 * MB);            // fp16 [512][512]
    u16*   wob   = (u16*)(ws + 1 * MB + 512 * 1024); // bf16 [512][512]
    float* stats = (float*)(ws + 2 * MB);          // 16 KB
    float* bqk   = (float*)(ws + 2 * MB + 64 * 1024); // fp32 [1024] concat bias
    u16*   xh    = (u16*)(ws + 4 * MB);            // 16 MB fp16 [16384][512]
    u16*   qkh   = (u16*)(ws + 20 * MB);           // 32 MB fp16 [16384][1024] (q | k)
    u16*   vt    = (u16*)(ws + 52 * MB);           // 16 MB bf16 [512][16384] (V^T)
    u16*   S     = (u16*)(ws + 68 * MB);           // 64 MB fp16 scores -> bf16 P in place
    u16*   feat  = (u16*)(ws + 132 * MB);          // 16 MB bf16
    float* lin   = (float*)(ws + 148 * MB);        // 32 MB fp32

    // bias concat (d2d async copies are graph-capture safe)
    hipMemcpyAsync(bqk,       bq, 512 * sizeof(float), hipMemcpyDeviceToDevice, stream);
    hipMemcpyAsync(bqk + 512, bk, 512 * sizeof(float), hipMemcpyDeviceToDevice, stream);

    // converts: x/Wq/Wk/Wv -> fp16; Wo -> bf16
    cvt16<1><<<8192, 256, 0, stream>>>(x,  xh,  2097152);
    cvt16<1><<<256,  256, 0, stream>>>(Wq, wqkh,          65536);
    cvt16<1><<<256,  256, 0, stream>>>(Wk, wqkh + 262144, 65536);
    cvt16<1><<<256,  256, 0, stream>>>(Wv, wvh, 65536);
    cvt16<0><<<256,  256, 0, stream>>>(Wo, wob, 65536);

    // [q|k] = x @ [Wq|Wk]^T + bqk   (M=16384, N=1024, K=512) fp16 out, ldc=1024
    gemm_nt<1, 2, 1><<<dim3(128, 8, 1), 256, 0, stream>>>(
        xh, 512, 0, wqkh, 512, 0, bqk, qkh, 1024, 0, 512);
    // v^T = Wv @ x^T + bv(row)  (fp16 MFMA -> bf16 out)  vt[a][m_global]
    gemm_nt<2, 0, 1><<<dim3(4, 128, 1), 256, 0, stream>>>(
        wvh, 512, 0, xh, 512, 0, bv, vt, MTOT, 0, 512);

    // S = q @ k^T  (all 8 batches; fp16 MFMA -> fp16 out)
    gemm_nt<0, 2, 1><<<dim3(16, 16, 8), 256, 0, stream>>>(
        qkh, 1024, (long)N_ * 1024,          // q: cols 0-511
        qkh + 512, 1024, (long)N_ * 1024,    // k: cols 512-1023
        nullptr, S, N_, (long)N_ * N_, 512);
    // softmax in place: fp16 scores -> bf16 P
    softmax_rows<<<MTOT, 256, 0, stream>>>(S);
    // feat = P @ v  (all 8 batches; bf16 MFMA; B = vt batch column slice)
    gemm_nt<0, 0, 0><<<dim3(16, 4, 8), 256, 0, stream>>>(
        S, N_, (long)N_ * N_,
        vt, MTOT, (long)N_,                  // batch z: vt + z*2048, ldb=16384
        nullptr, feat, A_, (long)N_ * A_, 2048);

    // lin = feat @ Wo^T + bo  (bf16 MFMA -> fp32)
    gemm_nt<1, 1, 0><<<dim3(128, 4, 1), 256, 0, stream>>>(
        feat, 512, 0, wob, 512, 0, bo, lin, 512, 0, 512);
    // BN stats per n, then BN+ReLU+residual
    bn_stats<<<2048, 256, 0, stream>>>(lin, stats);
    bn_relu_add<<<8192, 256, 0, stream>>>(lin, x, gamma, beta, stats, out);
}

// Round 5
// 238.691 us; speedup vs baseline: 1.2392x; 1.0288x over previous
//
#include <hip/hip_runtime.h>
#include <hip/hip_fp16.h>
#include <stdint.h>

// Problem constants (B=8, N=2048, F=512, A=512)
#define B_   8
#define N_   2048
#define F_   512
#define A_   512
#define MTOT (B_ * N_)   // 16384 rows total

typedef unsigned short u16;
typedef unsigned int   u32;
typedef __attribute__((ext_vector_type(8))) __bf16    bf16x8;
typedef __attribute__((ext_vector_type(8))) _Float16  f16x8;
typedef __attribute__((ext_vector_type(4))) float     f32x4;

// ---------- scalar converts ----------
__device__ __forceinline__ u16 f2bf(float f) {   // RNE
    u32 u = __builtin_bit_cast(u32, f);
    u32 r = u + 0x7fffu + ((u >> 16) & 1u);
    return (u16)(r >> 16);
}
__device__ __forceinline__ u16 f2h(float f) {    // RNE via HW cvt
    _Float16 h = (_Float16)f;
    return __builtin_bit_cast(u16, h);
}

// async global->LDS, 16B per lane (lds addr = uniform base + lane*16)
__device__ __forceinline__ void gload_lds16(const u16* g, u16* l) {
    __builtin_amdgcn_global_load_lds(
        (const __attribute__((address_space(1))) u32*)(const u32*)g,
        (__attribute__((address_space(3))) u32*)(u32*)l,
        16, 0, 0);
}

// ---------- fp32 -> {bf16|fp16} convert (4 elems/thread) ----------
template <int FMT>   // 0 = bf16, 1 = fp16
__global__ __launch_bounds__(256) void cvt16(const float* __restrict__ in,
                                             u16* __restrict__ out, int n4) {
    int i = blockIdx.x * 256 + threadIdx.x;
    if (i >= n4) return;
    float4 v = ((const float4*)in)[i];
    u32 a, b;
    if constexpr (FMT == 0) {
        a = (u32)f2bf(v.x) | ((u32)f2bf(v.y) << 16);
        b = (u32)f2bf(v.z) | ((u32)f2bf(v.w) << 16);
    } else {
        a = (u32)f2h(v.x) | ((u32)f2h(v.y) << 16);
        b = (u32)f2h(v.z) | ((u32)f2h(v.w) << 16);
    }
    ((uint2*)out)[i] = make_uint2(a, b);
}

// ================== 8-phase-style pipelined NT GEMM (fp16 in, fp16 out) =====
// C[m][n] = sum_k A[m][k]*B[n][k] (+bias[n] if BIAS). 256x256 tile, BK=32,
// 4-slot LDS ring (128 KiB), 8 waves (2M x 4N), counted vmcnt, XOR swizzle.
// Requires M%256==0, N%256==0, K%32==0, K>=128.
template <int BIAS_MODE>
__global__ __launch_bounds__(512)
void gemm8p(const u16* __restrict__ A, int lda, long sA,
            const u16* __restrict__ Bm, int ldb, long sB,
            const float* __restrict__ bias,
            u16* __restrict__ C, int ldc, long sC, int K)
{
    // ring: slot s (0..3): A-subtile [256][32] fp16 at s*16384, B at +8192
    __shared__ alignas(16) u16 lds8[65536];   // 128 KiB

    const int z = blockIdx.z;
    const int m0 = blockIdx.x * 256;
    const int n0 = blockIdx.y * 256;
    const u16* Ag = A  + (long)z * sA + (long)m0 * lda;
    const u16* Bg = Bm + (long)z * sB + (long)n0 * ldb;

    const int t = threadIdx.x;
    const int lane = t & 63, wave = t >> 6;
    const int wm = wave >> 2;          // 0..1  (M group, 128 rows)
    const int wn = wave & 3;           // 0..3  (N group, 64 cols)
    const int frow = lane & 15;
    const int fkel = (lane >> 4) * 8;  // k-element offset within 32

    const int NT = K >> 5;             // K/32 subtiles

    // stage one operand subtile (2 x 16B per thread), swizzled source
    auto stage2 = [&](const u16* g, int ld, int kel, u16* lbase) {
#pragma unroll
        for (int r = 0; r < 2; ++r) {
            int row = r * 128 + (t >> 2);
            int cel = ((t & 3) * 8) ^ ((row & 3) << 3);
            gload_lds16(g + (long)row * ld + kel + cel, lbase + r * 4096 + t * 8);
        }
    };
    // swizzled ds_read of one 16B fragment
    auto rd = [&](int base, int row) -> uint4 {
        return *(const uint4*)&lds8[base + row * 32 + (fkel ^ ((row & 3) << 3))];
    };

    f32x4 acc[8][4];
#pragma unroll
    for (int i = 0; i < 8; i++)
#pragma unroll
        for (int j = 0; j < 4; j++)
#pragma unroll
            for (int r = 0; r < 4; r++) acc[i][j][r] = 0.f;

    // prologue: stage subtiles 0,1,2 into slots 0,1,2 (12 loads/thread)
#pragma unroll
    for (int T = 0; T < 3; ++T) {
        stage2(Ag, lda, T * 32, &lds8[T * 16384]);
        stage2(Bg, ldb, T * 32, &lds8[T * 16384 + 8192]);
    }

    for (int T = 0; T < NT; ++T) {
        const int s  = (T & 3) * 16384;
        const int sn = ((T + 3) & 3) * 16384;
        const bool st = (T + 3 < NT);
        const int kel = (T + 3) * 32;

        // wait for subtile T's loads (counted: T+1,T+2 still in flight)
        if (T < NT - 2)      asm volatile("s_waitcnt vmcnt(8)" ::: "memory");
        else if (T == NT - 2) asm volatile("s_waitcnt vmcnt(4)" ::: "memory");
        else                 asm volatile("s_waitcnt vmcnt(0)" ::: "memory");
        __builtin_amdgcn_sched_barrier(0);
        __builtin_amdgcn_s_barrier();
        __builtin_amdgcn_sched_barrier(0);

        // ---- phase h0: rows wm*128 + [0,64), all 4 j; load B frags (reused in h1)
        uint4 ar[4], br[4];
#pragma unroll
        for (int i = 0; i < 4; i++) ar[i] = rd(s, wm * 128 + i * 16 + frow);
#pragma unroll
        for (int j = 0; j < 4; j++) br[j] = rd(s + 8192, wn * 64 + j * 16 + frow);
        if (st) stage2(Ag, lda, kel, &lds8[sn]);
        __builtin_amdgcn_s_setprio(1);
#pragma unroll
        for (int i = 0; i < 4; i++)
#pragma unroll
            for (int j = 0; j < 4; j++)
                acc[i][j] = __builtin_amdgcn_mfma_f32_16x16x32_f16(
                    __builtin_bit_cast(f16x8, ar[i]),
                    __builtin_bit_cast(f16x8, br[j]), acc[i][j], 0, 0, 0);
        __builtin_amdgcn_s_setprio(0);
        __builtin_amdgcn_sched_barrier(0);
        __builtin_amdgcn_s_barrier();
        __builtin_amdgcn_sched_barrier(0);

        // ---- phase h1: rows wm*128 + [64,128), B frags reused from registers
        uint4 ar2[4];
#pragma unroll
        for (int i = 0; i < 4; i++) ar2[i] = rd(s, wm * 128 + 64 + i * 16 + frow);
        if (st) stage2(Bg, ldb, kel, &lds8[sn + 8192]);
        __builtin_amdgcn_s_setprio(1);
#pragma unroll
        for (int i = 0; i < 4; i++)
#pragma unroll
            for (int j = 0; j < 4; j++)
                acc[4 + i][j] = __builtin_amdgcn_mfma_f32_16x16x32_f16(
                    __builtin_bit_cast(f16x8, ar2[i]),
                    __builtin_bit_cast(f16x8, br[j]), acc[4 + i][j], 0, 0, 0);
        __builtin_amdgcn_s_setprio(0);
    }

    // epilogue: C/D layout col = lane&15, row = (lane>>4)*4 + r
    const int q4 = (lane >> 4) * 4;
#pragma unroll
    for (int ii = 0; ii < 8; ii++) {
        // acc[ii] covers rows wm*128 + (ii>>2)*64 + (ii&3)*16
        int m = m0 + wm * 128 + (ii >> 2) * 64 + (ii & 3) * 16 + q4;
#pragma unroll
        for (int j = 0; j < 4; j++) {
            int n = n0 + wn * 64 + j * 16 + frow;
            float badd = 0.f;
            if (BIAS_MODE == 1) badd = bias[n];
#pragma unroll
            for (int r = 0; r < 4; r++)
                C[(long)(m + r) * ldc + n + (long)z * sC] = f2h(acc[ii][j][r] + badd);
        }
    }
}

// ---------- NT GEMM (m97 structure): kept for PV / v^T / Wo ----------
// BIAS_MODE: 0 none, 1 bias[n], 2 bias[m]. OUT_FMT: 0 bf16, 1 fp32, 2 fp16.
// IN_FMT: 0 bf16 MFMA, 1 fp16 MFMA.
template <int BIAS_MODE, int OUT_FMT, int IN_FMT>
__global__ __launch_bounds__(256)
void gemm_nt(const u16* __restrict__ A, int lda, long sA,
             const u16* __restrict__ Bm, int ldb, long sB,
             const float* __restrict__ bias,
             void* __restrict__ Cv, int ldc, long sC, int K)
{
    __shared__ alignas(16) u16 lA[128 * 64];
    __shared__ alignas(16) u16 lB[128 * 64];

    const int z = blockIdx.z;
    A  += (long)z * sA;
    Bm += (long)z * sB;

    const int m0 = blockIdx.x * 128;
    const int n0 = blockIdx.y * 128;
    const int t = threadIdx.x;
    const int lane = t & 63, wave = t >> 6;
    const int wr = (wave >> 1) * 64;
    const int wc = (wave & 1) * 64;
    const int frow = lane & 15;
    const int fk   = (lane >> 4) * 8;

    f32x4 acc[4][4];
#pragma unroll
    for (int i = 0; i < 4; i++)
#pragma unroll
        for (int j = 0; j < 4; j++)
#pragma unroll
            for (int r = 0; r < 4; r++) acc[i][j][r] = 0.f;

    const int srow = t >> 3;
    const int scol = (t & 7) * 8;

    for (int kt = 0; kt < K; kt += 64) {
        __syncthreads();
#pragma unroll
        for (int s = 0; s < 4; ++s) {
            int row = s * 32 + srow;
            const u16* ga = A  + (long)(m0 + row) * lda + (kt + scol);
            const u16* gb = Bm + (long)(n0 + row) * ldb + (kt + scol);
            gload_lds16(ga, &lA[s * 2048 + t * 8]);
            gload_lds16(gb, &lB[s * 2048 + t * 8]);
        }
        __syncthreads();
#pragma unroll
        for (int kk = 0; kk < 64; kk += 32) {
            uint4 ar[4], br[4];
#pragma unroll
            for (int i = 0; i < 4; i++)
                ar[i] = *(const uint4*)&lA[(wr + i * 16 + frow) * 64 + kk + fk];
#pragma unroll
            for (int j = 0; j < 4; j++)
                br[j] = *(const uint4*)&lB[(wc + j * 16 + frow) * 64 + kk + fk];
#pragma unroll
            for (int i = 0; i < 4; i++)
#pragma unroll
                for (int j = 0; j < 4; j++) {
                    if constexpr (IN_FMT == 0)
                        acc[i][j] = __builtin_amdgcn_mfma_f32_16x16x32_bf16(
                            __builtin_bit_cast(bf16x8, ar[i]),
                            __builtin_bit_cast(bf16x8, br[j]),
                            acc[i][j], 0, 0, 0);
                    else
                        acc[i][j] = __builtin_amdgcn_mfma_f32_16x16x32_f16(
                            __builtin_bit_cast(f16x8, ar[i]),
                            __builtin_bit_cast(f16x8, br[j]),
                            acc[i][j], 0, 0, 0);
                }
        }
    }

    const int rbase = (lane >> 4) * 4;
#pragma unroll
    for (int i = 0; i < 4; i++) {
        int m = m0 + wr + i * 16 + rbase;
#pragma unroll
        for (int j = 0; j < 4; j++) {
            int n = n0 + wc + j * 16 + frow;
            float badd = 0.f;
            if (BIAS_MODE == 1) badd = bias[n];
#pragma unroll
            for (int r = 0; r < 4; r++) {
                float v = acc[i][j][r];
                if (BIAS_MODE == 1) v += badd;
                if (BIAS_MODE == 2) v += bias[m + r];
                long idx = (long)(m + r) * ldc + n + (long)z * sC;
                if constexpr (OUT_FMT == 0) {
                    ((u16*)Cv)[idx] = f2bf(v);
                } else if constexpr (OUT_FMT == 1) {
                    ((float*)Cv)[idx] = v;
                } else {
                    ((u16*)Cv)[idx] = f2h(v);
                }
            }
        }
    }
}

// ---------- row softmax: fp16 scores in, bf16 weights out, in place ----------
__global__ __launch_bounds__(256) void softmax_rows(u16* __restrict__ S) {
    __shared__ float red[16];
    const long row = blockIdx.x;
    u16* p = S + row * (long)N_;
    const int t = threadIdx.x;
    const int lane = t & 63, wave = t >> 6;

    uint4 raw = ((const uint4*)p)[t];   // 8 fp16 per thread
    const __half2* hp = (const __half2*)&raw;
    float v[8];
#pragma unroll
    for (int j = 0; j < 4; j++) {
        float2 f = __half22float2(hp[j]);
        v[2 * j]     = f.x;
        v[2 * j + 1] = f.y;
    }
    float mx = v[0];
#pragma unroll
    for (int j = 1; j < 8; j++) mx = fmaxf(mx, v[j]);
#pragma unroll
    for (int o = 32; o; o >>= 1) mx = fmaxf(mx, __shfl_xor(mx, o));
    if (lane == 0) red[wave] = mx;
    __syncthreads();
    mx = fmaxf(fmaxf(red[0], red[1]), fmaxf(red[2], red[3]));

    float s = 0.f;
#pragma unroll
    for (int j = 0; j < 8; j++) { v[j] = __expf(v[j] - mx); s += v[j]; }
#pragma unroll
    for (int o = 32; o; o >>= 1) s += __shfl_xor(s, o);
    if (lane == 0) red[8 + wave] = s;
    __syncthreads();
    s = red[8] + red[9] + red[10] + red[11];
    float inv = 1.f / s;
    u32 w[4];
#pragma unroll
    for (int j = 0; j < 4; j++) {
        u32 lo = f2bf(v[2 * j] * inv);
        u32 hi = f2bf(v[2 * j + 1] * inv);
        w[j] = lo | (hi << 16);
    }
    ((uint4*)p)[t] = make_uint4(w[0], w[1], w[2], w[3]);
}

// ---------- BN stats: per n over (b,f): 4096 values -> mean, rstd ----------
__global__ __launch_bounds__(256) void bn_stats(const float* __restrict__ lin,
                                                float* __restrict__ stats) {
    __shared__ float red[16];
    const int n = blockIdx.x;
    const int t = threadIdx.x;
    const int lane = t & 63, wave = t >> 6;
    float s = 0.f, s2 = 0.f;
    for (int idx = t; idx < 1024; idx += 256) {
        int b = idx >> 7, f4 = idx & 127;
        float4 x = ((const float4*)(lin + ((long)b * N_ + n) * F_))[f4];
        s  += x.x + x.y + x.z + x.w;
        s2 += x.x * x.x + x.y * x.y + x.z * x.z + x.w * x.w;
    }
#pragma unroll
    for (int o = 32; o; o >>= 1) { s += __shfl_xor(s, o); s2 += __shfl_xor(s2, o); }
    if (lane == 0) { red[wave] = s; red[8 + wave] = s2; }
    __syncthreads();
    if (t == 0) {
        float S1 = red[0] + red[1] + red[2] + red[3];
        float S2 = red[8] + red[9] + red[10] + red[11];
        float mean = S1 / 4096.f;
        float var  = S2 / 4096.f - mean * mean;
        stats[n]      = mean;
        stats[N_ + n] = rsqrtf(var + 1e-5f);
    }
}

// ---------- BN apply + ReLU + residual ----------
__global__ __launch_bounds__(256)
void bn_relu_add(const float* __restrict__ lin, const float* __restrict__ x,
                 const float* __restrict__ gamma, const float* __restrict__ beta,
                 const float* __restrict__ stats, float* __restrict__ out) {
    long i4 = (long)blockIdx.x * 256 + threadIdx.x;
    int n = (int)((i4 >> 7) & (N_ - 1));
    float mean = stats[n], rstd = stats[N_ + n];
    float scale = gamma[n] * rstd;
    float shift = beta[n] - mean * scale;
    float4 l  = ((const float4*)lin)[i4];
    float4 xx = ((const float4*)x)[i4];
    float4 o;
    o.x = fmaxf(l.x * scale + shift, 0.f) + xx.x;
    o.y = fmaxf(l.y * scale + shift, 0.f) + xx.y;
    o.z = fmaxf(l.z * scale + shift, 0.f) + xx.z;
    o.w = fmaxf(l.w * scale + shift, 0.f) + xx.w;
    ((float4*)out)[i4] = o;
}

extern "C" void kernel_launch(void* const* d_in, const int* in_sizes, int n_in,
                              void* d_out, int out_size, void* d_ws, size_t ws_size,
                              hipStream_t stream)
{
    (void)in_sizes; (void)n_in; (void)out_size; (void)ws_size;
    const float* x     = (const float*)d_in[0];
    const float* Wq    = (const float*)d_in[1];
    const float* bq    = (const float*)d_in[2];
    const float* Wk    = (const float*)d_in[3];
    const float* bk    = (const float*)d_in[4];
    const float* Wv    = (const float*)d_in[5];
    const float* bv    = (const float*)d_in[6];
    const float* Wo    = (const float*)d_in[7];
    const float* bo    = (const float*)d_in[8];
    const float* gamma = (const float*)d_in[9];
    const float* beta  = (const float*)d_in[10];
    float* out = (float*)d_out;
    char*  ws  = (char*)d_ws;

    const size_t MB = 1024 * 1024;
    u16*   wqkh  = (u16*)(ws + 0);                 // fp16 [1024][512]: Wq | Wk
    u16*   wvh   = (u16*)(ws + 1 * MB);            // fp16 [512][512]
    u16*   wob   = (u16*)(ws + 1 * MB + 512 * 1024); // bf16 [512][512]
    float* stats = (float*)(ws + 2 * MB);          // 16 KB
    float* bqk   = (float*)(ws + 2 * MB + 64 * 1024); // fp32 [1024]
    u16*   xh    = (u16*)(ws + 4 * MB);            // 16 MB fp16 [16384][512]
    u16*   qkh   = (u16*)(ws + 20 * MB);           // 32 MB fp16 [16384][1024]
    u16*   vt    = (u16*)(ws + 52 * MB);           // 16 MB bf16 [512][16384]
    u16*   S     = (u16*)(ws + 68 * MB);           // 64 MB fp16 -> bf16 in place
    u16*   feat  = (u16*)(ws + 132 * MB);          // 16 MB bf16
    float* lin   = (float*)(ws + 148 * MB);        // 32 MB fp32

    hipMemcpyAsync(bqk,       bq, 512 * sizeof(float), hipMemcpyDeviceToDevice, stream);
    hipMemcpyAsync(bqk + 512, bk, 512 * sizeof(float), hipMemcpyDeviceToDevice, stream);

    cvt16<1><<<8192, 256, 0, stream>>>(x,  xh,  2097152);
    cvt16<1><<<256,  256, 0, stream>>>(Wq, wqkh,          65536);
    cvt16<1><<<256,  256, 0, stream>>>(Wk, wqkh + 262144, 65536);
    cvt16<1><<<256,  256, 0, stream>>>(Wv, wvh, 65536);
    cvt16<0><<<256,  256, 0, stream>>>(Wo, wob, 65536);

    // [q|k] = x @ [Wq|Wk]^T + bqk  (8-phase pipelined, fp16)
    gemm8p<1><<<dim3(64, 4, 1), 512, 0, stream>>>(
        xh, 512, 0, wqkh, 512, 0, bqk, qkh, 1024, 0, 512);
    // v^T = Wv @ x^T + bv(row)  (m97 structure)
    gemm_nt<2, 0, 1><<<dim3(4, 128, 1), 256, 0, stream>>>(
        wvh, 512, 0, xh, 512, 0, bv, vt, MTOT, 0, 512);

    // S = q @ k^T  (8-phase pipelined, all 8 batches, fp16 out)
    gemm8p<0><<<dim3(8, 8, 8), 512, 0, stream>>>(
        qkh, 1024, (long)N_ * 1024,
        qkh + 512, 1024, (long)N_ * 1024,
        nullptr, S, N_, (long)N_ * N_, 512);
    // softmax in place: fp16 scores -> bf16 P
    softmax_rows<<<MTOT, 256, 0, stream>>>(S);
    // feat = P @ v  (m97 structure, bf16)
    gemm_nt<0, 0, 0><<<dim3(16, 4, 8), 256, 0, stream>>>(
        S, N_, (long)N_ * N_,
        vt, MTOT, (long)N_,
        nullptr, feat, A_, (long)N_ * A_, 2048);

    // lin = feat @ Wo^T + bo
    gemm_nt<1, 1, 0><<<dim3(128, 4, 1), 256, 0, stream>>>(
        feat, 512, 0, wob, 512, 0, bo, lin, 512, 0, 512);
    bn_stats<<<2048, 256, 0, stream>>>(lin, stats);
    bn_relu_add<<<8192, 256, 0, stream>>>(lin, x, gamma, beta, stats, out);
}

// Round 6
// 214.234 us; speedup vs baseline: 1.3806x; 1.1142x over previous
//
#include <hip/hip_runtime.h>
#include <hip/hip_fp16.h>
#include <stdint.h>

// Problem constants (B=8, N=2048, F=512, A=512)
#define B_   8
#define N_   2048
#define F_   512
#define A_   512
#define MTOT (B_ * N_)   // 16384 rows total

typedef unsigned short u16;
typedef unsigned int   u32;
typedef __attribute__((ext_vector_type(8))) __bf16    bf16x8;
typedef __attribute__((ext_vector_type(8))) _Float16  f16x8;
typedef __attribute__((ext_vector_type(4))) float     f32x4;

// ---------- scalar converts ----------
__device__ __forceinline__ u16 f2bf(float f) {   // RNE
    u32 u = __builtin_bit_cast(u32, f);
    u32 r = u + 0x7fffu + ((u >> 16) & 1u);
    return (u16)(r >> 16);
}
__device__ __forceinline__ u16 f2h(float f) {    // RNE via HW cvt
    _Float16 h = (_Float16)f;
    return __builtin_bit_cast(u16, h);
}

// async global->LDS, 16B per lane (linear lane-ordered dest)
__device__ __forceinline__ void gload_lds16(const u16* g, u16* l) {
    __builtin_amdgcn_global_load_lds(
        (const __attribute__((address_space(1))) u32*)(const u32*)g,
        (__attribute__((address_space(3))) u32*)(u32*)l,
        16, 0, 0);
}

#define VMCNT(n) asm volatile("s_waitcnt vmcnt(" #n ")" ::: "memory")

__device__ __forceinline__ void sync_pre() {
    __builtin_amdgcn_sched_barrier(0);
    __builtin_amdgcn_s_barrier();
    asm volatile("s_waitcnt lgkmcnt(0)" ::: "memory");
    __builtin_amdgcn_sched_barrier(0);
}
__device__ __forceinline__ void sync_post() {
    __builtin_amdgcn_sched_barrier(0);
    __builtin_amdgcn_s_barrier();
}

// ---------- fp32 -> {bf16|fp16} convert (4 elems/thread) ----------
template <int FMT>   // 0 = bf16, 1 = fp16
__global__ __launch_bounds__(256) void cvt16(const float* __restrict__ in,
                                             u16* __restrict__ out, int n4) {
    int i = blockIdx.x * 256 + threadIdx.x;
    if (i >= n4) return;
    float4 v = ((const float4*)in)[i];
    u32 a, b;
    if constexpr (FMT == 0) {
        a = (u32)f2bf(v.x) | ((u32)f2bf(v.y) << 16);
        b = (u32)f2bf(v.z) | ((u32)f2bf(v.w) << 16);
    } else {
        a = (u32)f2h(v.x) | ((u32)f2h(v.y) << 16);
        b = (u32)f2h(v.z) | ((u32)f2h(v.w) << 16);
    }
    ((uint2*)out)[i] = make_uint2(a, b);
}

// ============ 8-phase pipelined NT GEMM (m201-style schedule) ============
// C[m][n] = sum_k A[m][k]*B[n][k] (+bias). BM=256, BK=64, 8 waves (2M x 4N).
// BN: 256 (4 phases/K-tile) or 128 (2 phases/K-tile). 16 MFMA per phase.
// LDS: 2 buffers x UNITS x 16KB half-tiles; stage 1 half/phase into the
// inactive buffer, issue-order == use-order, counted vmcnt (never 0 mid-loop).
// XOR swizzle el^=(rr&7)<<3 on pre-swizzled global source + ds_read.
// BIAS_MODE: 0 none, 1 bias[n], 2 bias[m]. OUT_FMT: 0 bf16, 1 fp32, 2 fp16.
// IN_FMT: 0 bf16 MFMA, 1 fp16 MFMA. bdiag: B += (m0>>11)*bdiag (PV batching).
// Requires M%256==0, N%BN==0, K%64==0.
template <int BN, int BIAS_MODE, int OUT_FMT, int IN_FMT>
__global__ __launch_bounds__(512, 2)
void gemm8(const u16* __restrict__ A, int lda, long sA,
           const u16* __restrict__ Bm, int ldb, long sB,
           const float* __restrict__ bias,
           void* __restrict__ Cv, int ldc, long sC, int K, int bdiag)
{
    constexpr int UNITS = (BN == 256) ? 4 : 3;   // A0,A1,B0[,B1]
    constexpr int NF = BN / 64;                  // n-frags per wave (4 or 2)
    __shared__ alignas(16) u16 lds[2 * UNITS * 8192];

    const int z  = blockIdx.z;
    const int m0 = blockIdx.x * 256;
    const int n0 = blockIdx.y * BN;
    const u16* Ag = A  + (long)z * sA + (long)m0 * lda;
    const u16* Bg = Bm + (long)z * sB + (long)n0 * ldb + (long)(m0 >> 11) * bdiag;

    const int t = threadIdx.x;
    const int lane = t & 63;
    const int wave = t >> 6;
    const int wm = wave >> 2, wn = wave & 3;
    const int frow = lane & 15;
    const int fk8 = (lane >> 4) * 8;

    // staging geometry: thread t, round r covers within-half row rr = r*64+(t>>3),
    // swizzled el slot (t&7)*8; source el pre-swizzled so LDS stays linear.
    const int srr = t >> 3;
    const int ses = ((t & 7) * 8) ^ ((srr & 7) << 3);

    // A half h = tile rows {h*64+[0,64)} u {128+h*64+[0,64)}  (per-wave quads)
    auto stageA = [&](int buf, int h, int kt) {
        u16* dst = &lds[(buf * UNITS + h) * 8192 + t * 8];
        const u16* g = Ag + kt * 64 + ses;
        gload_lds16(g + (long)(srr + h * 64) * lda,        dst);
        gload_lds16(g + (long)(srr + 128 + h * 64) * lda,  dst + 4096);
    };
    // B: BN==256: half h = cols {(rr&31)+((rr>>5)<<6)+h*32}; BN==128: one unit
    auto stageB = [&](int buf, int h, int kt) {
        u16* dst = &lds[(buf * UNITS + 2 + h) * 8192 + t * 8];
        const u16* g = Bg + kt * 64 + ses;
        int R0;
        if constexpr (BN == 256) R0 = (srr & 31) + ((srr >> 5) << 6) + h * 32;
        else                     R0 = srr;
        int R1 = R0 + ((BN == 256) ? 128 : 64);
        gload_lds16(g + (long)R0 * ldb, dst);
        gload_lds16(g + (long)R1 * ldb, dst + 4096);
    };
    auto rdA = [&](int buf, int q, int i, int ks) -> uint4 {
        int rr = wm * 64 + i * 16 + frow;
        int e  = (ks * 32 + fk8) ^ ((rr & 7) << 3);
        return *(const uint4*)&lds[(buf * UNITS + q) * 8192 + rr * 64 + e];
    };
    auto rdB = [&](int buf, int p, int j, int ks) -> uint4 {
        int rr = wn * 32 + j * 16 + frow;
        int e  = (ks * 32 + fk8) ^ ((rr & 7) << 3);
        return *(const uint4*)&lds[(buf * UNITS + 2 + p) * 8192 + rr * 64 + e];
    };
    auto MF = [&](uint4 a, uint4 b, f32x4 c) -> f32x4 {
        if constexpr (IN_FMT == 0)
            return __builtin_amdgcn_mfma_f32_16x16x32_bf16(
                __builtin_bit_cast(bf16x8, a), __builtin_bit_cast(bf16x8, b), c, 0, 0, 0);
        else
            return __builtin_amdgcn_mfma_f32_16x16x32_f16(
                __builtin_bit_cast(f16x8, a), __builtin_bit_cast(f16x8, b), c, 0, 0, 0);
    };

    f32x4 acc[8][NF];
#pragma unroll
    for (int i = 0; i < 8; i++)
#pragma unroll
        for (int j = 0; j < NF; j++)
#pragma unroll
            for (int r = 0; r < 4; r++) acc[i][j][r] = 0.f;

    uint4 fa[4][2], fb0[2][2], fb1[2][2];
    const int NT = K >> 6;   // K/64 tiles

    // ---- prologue: stage tile 0 in use-order, wait first two halves ----
    if constexpr (BN == 256) {
        stageA(0, 0, 0); stageB(0, 0, 0); stageB(0, 1, 0); stageA(0, 1, 0);
        VMCNT(4);
    } else {
        stageA(0, 0, 0); stageB(0, 0, 0); stageA(0, 1, 0);
        VMCNT(2);
    }
    __builtin_amdgcn_sched_barrier(0);
    __builtin_amdgcn_s_barrier();

    for (int kt = 0; kt < NT; ++kt) {
        const int buf = kt & 1, nb = buf ^ 1;
        const bool st = (kt + 1 < NT);

        if constexpr (BN == 256) {
            // ---- ph1: read A0 + B0; stage A0(t+1); quad (m0,n0)
#pragma unroll
            for (int i = 0; i < 4; i++) { fa[i][0] = rdA(buf, 0, i, 0); fa[i][1] = rdA(buf, 0, i, 1); }
#pragma unroll
            for (int j = 0; j < 2; j++) { fb0[j][0] = rdB(buf, 0, j, 0); fb0[j][1] = rdB(buf, 0, j, 1); }
            if (st) { stageA(nb, 0, kt + 1); VMCNT(4); } else VMCNT(2);
            sync_pre();
            __builtin_amdgcn_s_setprio(1);
#pragma unroll
            for (int ks = 0; ks < 2; ks++)
#pragma unroll
                for (int i = 0; i < 4; i++)
#pragma unroll
                    for (int j = 0; j < 2; j++)
                        acc[i][j] = MF(fa[i][ks], fb0[j][ks], acc[i][j]);
            __builtin_amdgcn_s_setprio(0);
            sync_post();
            // ---- ph2: read B1; stage B0(t+1); quad (m0,n1)
#pragma unroll
            for (int j = 0; j < 2; j++) { fb1[j][0] = rdB(buf, 1, j, 0); fb1[j][1] = rdB(buf, 1, j, 1); }
            if (st) { stageB(nb, 0, kt + 1); VMCNT(4); } else VMCNT(0);
            sync_pre();
            __builtin_amdgcn_s_setprio(1);
#pragma unroll
            for (int ks = 0; ks < 2; ks++)
#pragma unroll
                for (int i = 0; i < 4; i++)
#pragma unroll
                    for (int j = 0; j < 2; j++)
                        acc[i][2 + j] = MF(fa[i][ks], fb1[j][ks], acc[i][2 + j]);
            __builtin_amdgcn_s_setprio(0);
            sync_post();
            // ---- ph3: read A1; stage B1(t+1); quad (m1,n0)
#pragma unroll
            for (int i = 0; i < 4; i++) { fa[i][0] = rdA(buf, 1, i, 0); fa[i][1] = rdA(buf, 1, i, 1); }
            if (st) stageB(nb, 1, kt + 1);
            sync_pre();
            __builtin_amdgcn_s_setprio(1);
#pragma unroll
            for (int ks = 0; ks < 2; ks++)
#pragma unroll
                for (int i = 0; i < 4; i++)
#pragma unroll
                    for (int j = 0; j < 2; j++)
                        acc[4 + i][j] = MF(fa[i][ks], fb0[j][ks], acc[4 + i][j]);
            __builtin_amdgcn_s_setprio(0);
            sync_post();
            // ---- ph4: stage A1(t+1); quad (m1,n1)
            if (st) { stageA(nb, 1, kt + 1); VMCNT(4); }
            sync_pre();
            __builtin_amdgcn_s_setprio(1);
#pragma unroll
            for (int ks = 0; ks < 2; ks++)
#pragma unroll
                for (int i = 0; i < 4; i++)
#pragma unroll
                    for (int j = 0; j < 2; j++)
                        acc[4 + i][2 + j] = MF(fa[i][ks], fb1[j][ks], acc[4 + i][2 + j]);
            __builtin_amdgcn_s_setprio(0);
            sync_post();
        } else {
            // ---- ph1: read A0 + B; stage A0(t+1), B(t+1); quad m0
#pragma unroll
            for (int i = 0; i < 4; i++) { fa[i][0] = rdA(buf, 0, i, 0); fa[i][1] = rdA(buf, 0, i, 1); }
#pragma unroll
            for (int j = 0; j < 2; j++) { fb0[j][0] = rdB(buf, 0, j, 0); fb0[j][1] = rdB(buf, 0, j, 1); }
            if (st) { stageA(nb, 0, kt + 1); stageB(nb, 0, kt + 1); VMCNT(4); } else VMCNT(0);
            sync_pre();
            __builtin_amdgcn_s_setprio(1);
#pragma unroll
            for (int ks = 0; ks < 2; ks++)
#pragma unroll
                for (int i = 0; i < 4; i++)
#pragma unroll
                    for (int j = 0; j < 2; j++)
                        acc[i][j] = MF(fa[i][ks], fb0[j][ks], acc[i][j]);
            __builtin_amdgcn_s_setprio(0);
            sync_post();
            // ---- ph2: read A1; stage A1(t+1); quad m1
#pragma unroll
            for (int i = 0; i < 4; i++) { fa[i][0] = rdA(buf, 1, i, 0); fa[i][1] = rdA(buf, 1, i, 1); }
            if (st) { stageA(nb, 1, kt + 1); VMCNT(2); }
            sync_pre();
            __builtin_amdgcn_s_setprio(1);
#pragma unroll
            for (int ks = 0; ks < 2; ks++)
#pragma unroll
                for (int i = 0; i < 4; i++)
#pragma unroll
                    for (int j = 0; j < 2; j++)
                        acc[4 + i][j] = MF(fa[i][ks], fb0[j][ks], acc[4 + i][j]);
            __builtin_amdgcn_s_setprio(0);
            sync_post();
        }
    }

    // ---- epilogue: C/D layout col = lane&15, row = (lane>>4)*4 + r ----
    const int rq = (lane >> 4) * 4;
#pragma unroll
    for (int am = 0; am < 8; am++) {
        const int m = m0 + wm * 128 + (am >> 2) * 64 + (am & 3) * 16 + rq;
#pragma unroll
        for (int an = 0; an < NF; an++) {
            const int n = n0 + wn * (BN / 4) + an * 16 + frow;
            float badd = 0.f;
            if (BIAS_MODE == 1) badd = bias[n];
#pragma unroll
            for (int r = 0; r < 4; r++) {
                float v = acc[am][an][r];
                if (BIAS_MODE == 1) v += badd;
                if (BIAS_MODE == 2) v += bias[m + r];
                long idx = (long)(m + r) * ldc + n + (long)z * sC;
                if constexpr (OUT_FMT == 0)      ((u16*)Cv)[idx] = f2bf(v);
                else if constexpr (OUT_FMT == 1) ((float*)Cv)[idx] = v;
                else                             ((u16*)Cv)[idx] = f2h(v);
            }
        }
    }
}

// ---------- row softmax: fp16 scores in, bf16 weights out, in place ----------
__global__ __launch_bounds__(256) void softmax_rows(u16* __restrict__ S) {
    __shared__ float red[16];
    const long row = blockIdx.x;
    u16* p = S + row * (long)N_;
    const int t = threadIdx.x;
    const int lane = t & 63, wave = t >> 6;

    uint4 raw = ((const uint4*)p)[t];   // 8 fp16 per thread
    const __half2* hp = (const __half2*)&raw;
    float v[8];
#pragma unroll
    for (int j = 0; j < 4; j++) {
        float2 f = __half22float2(hp[j]);
        v[2 * j]     = f.x;
        v[2 * j + 1] = f.y;
    }
    float mx = v[0];
#pragma unroll
    for (int j = 1; j < 8; j++) mx = fmaxf(mx, v[j]);
#pragma unroll
    for (int o = 32; o; o >>= 1) mx = fmaxf(mx, __shfl_xor(mx, o));
    if (lane == 0) red[wave] = mx;
    __syncthreads();
    mx = fmaxf(fmaxf(red[0], red[1]), fmaxf(red[2], red[3]));

    float s = 0.f;
#pragma unroll
    for (int j = 0; j < 8; j++) { v[j] = __expf(v[j] - mx); s += v[j]; }
#pragma unroll
    for (int o = 32; o; o >>= 1) s += __shfl_xor(s, o);
    if (lane == 0) red[8 + wave] = s;
    __syncthreads();
    s = red[8] + red[9] + red[10] + red[11];
    float inv = 1.f / s;
    u32 w[4];
#pragma unroll
    for (int j = 0; j < 4; j++) {
        u32 lo = f2bf(v[2 * j] * inv);
        u32 hi = f2bf(v[2 * j + 1] * inv);
        w[j] = lo | (hi << 16);
    }
    ((uint4*)p)[t] = make_uint4(w[0], w[1], w[2], w[3]);
}

// ---------- BN stats: per n over (b,f): 4096 values -> mean, rstd ----------
__global__ __launch_bounds__(256) void bn_stats(const float* __restrict__ lin,
                                                float* __restrict__ stats) {
    __shared__ float red[16];
    const int n = blockIdx.x;
    const int t = threadIdx.x;
    const int lane = t & 63, wave = t >> 6;
    float s = 0.f, s2 = 0.f;
    for (int idx = t; idx < 1024; idx += 256) {
        int b = idx >> 7, f4 = idx & 127;
        float4 x = ((const float4*)(lin + ((long)b * N_ + n) * F_))[f4];
        s  += x.x + x.y + x.z + x.w;
        s2 += x.x * x.x + x.y * x.y + x.z * x.z + x.w * x.w;
    }
#pragma unroll
    for (int o = 32; o; o >>= 1) { s += __shfl_xor(s, o); s2 += __shfl_xor(s2, o); }
    if (lane == 0) { red[wave] = s; red[8 + wave] = s2; }
    __syncthreads();
    if (t == 0) {
        float S1 = red[0] + red[1] + red[2] + red[3];
        float S2 = red[8] + red[9] + red[10] + red[11];
        float mean = S1 / 4096.f;
        float var  = S2 / 4096.f - mean * mean;
        stats[n]      = mean;
        stats[N_ + n] = rsqrtf(var + 1e-5f);
    }
}

// ---------- BN apply + ReLU + residual ----------
__global__ __launch_bounds__(256)
void bn_relu_add(const float* __restrict__ lin, const float* __restrict__ x,
                 const float* __restrict__ gamma, const float* __restrict__ beta,
                 const float* __restrict__ stats, float* __restrict__ out) {
    long i4 = (long)blockIdx.x * 256 + threadIdx.x;
    int n = (int)((i4 >> 7) & (N_ - 1));
    float mean = stats[n], rstd = stats[N_ + n];
    float scale = gamma[n] * rstd;
    float shift = beta[n] - mean * scale;
    float4 l  = ((const float4*)lin)[i4];
    float4 xx = ((const float4*)x)[i4];
    float4 o;
    o.x = fmaxf(l.x * scale + shift, 0.f) + xx.x;
    o.y = fmaxf(l.y * scale + shift, 0.f) + xx.y;
    o.z = fmaxf(l.z * scale + shift, 0.f) + xx.z;
    o.w = fmaxf(l.w * scale + shift, 0.f) + xx.w;
    ((float4*)out)[i4] = o;
}

extern "C" void kernel_launch(void* const* d_in, const int* in_sizes, int n_in,
                              void* d_out, int out_size, void* d_ws, size_t ws_size,
                              hipStream_t stream)
{
    (void)in_sizes; (void)n_in; (void)out_size; (void)ws_size;
    const float* x     = (const float*)d_in[0];
    const float* Wq    = (const float*)d_in[1];
    const float* bq    = (const float*)d_in[2];
    const float* Wk    = (const float*)d_in[3];
    const float* bk    = (const float*)d_in[4];
    const float* Wv    = (const float*)d_in[5];
    const float* bv    = (const float*)d_in[6];
    const float* Wo    = (const float*)d_in[7];
    const float* bo    = (const float*)d_in[8];
    const float* gamma = (const float*)d_in[9];
    const float* beta  = (const float*)d_in[10];
    float* out = (float*)d_out;
    char*  ws  = (char*)d_ws;

    const size_t MB = 1024 * 1024;
    u16*   wqkh  = (u16*)(ws + 0);                 // fp16 [1024][512]: Wq | Wk
    u16*   wvh   = (u16*)(ws + 1 * MB);            // fp16 [512][512]
    u16*   wob   = (u16*)(ws + 1 * MB + 512 * 1024); // bf16 [512][512]
    float* stats = (float*)(ws + 2 * MB);          // 16 KB
    float* bqk   = (float*)(ws + 2 * MB + 64 * 1024); // fp32 [1024]
    u16*   xh    = (u16*)(ws + 4 * MB);            // 16 MB fp16 [16384][512]
    u16*   qkh   = (u16*)(ws + 20 * MB);           // 32 MB fp16 [16384][1024]
    u16*   vt    = (u16*)(ws + 52 * MB);           // 16 MB bf16 [512][16384]
    u16*   S     = (u16*)(ws + 68 * MB);           // 64 MB fp16 -> bf16 in place
    u16*   feat  = (u16*)(ws + 132 * MB);          // 16 MB bf16
    float* lin   = (float*)(ws + 148 * MB);        // 32 MB fp32

    hipMemcpyAsync(bqk,       bq, 512 * sizeof(float), hipMemcpyDeviceToDevice, stream);
    hipMemcpyAsync(bqk + 512, bk, 512 * sizeof(float), hipMemcpyDeviceToDevice, stream);

    cvt16<1><<<8192, 256, 0, stream>>>(x,  xh,  2097152);
    cvt16<1><<<256,  256, 0, stream>>>(Wq, wqkh,          65536);
    cvt16<1><<<256,  256, 0, stream>>>(Wk, wqkh + 262144, 65536);
    cvt16<1><<<256,  256, 0, stream>>>(Wv, wvh, 65536);
    cvt16<0><<<256,  256, 0, stream>>>(Wo, wob, 65536);

    // [q|k] = x @ [Wq|Wk]^T + bqk   (M=16384, N=1024, K=512) fp16
    gemm8<256, 1, 2, 1><<<dim3(64, 4, 1), 512, 0, stream>>>(
        xh, 512, 0, wqkh, 512, 0, bqk, qkh, 1024, 0, 512, 0);
    // v^T = Wv @ x^T + bv(row)   (M=512, N=16384, K=512) -> vt[a][token] bf16
    gemm8<128, 2, 0, 1><<<dim3(2, 128, 1), 512, 0, stream>>>(
        wvh, 512, 0, xh, 512, 0, bv, vt, MTOT, 0, 512, 0);
    // S = q @ k^T   (batched z=8, M=N=2048, K=512) fp16 scores
    gemm8<256, 0, 2, 1><<<dim3(8, 8, 8), 512, 0, stream>>>(
        qkh, 1024, (long)N_ * 1024, qkh + 512, 1024, (long)N_ * 1024,
        nullptr, S, N_, (long)N_ * N_, 512, 0);
    // softmax in place: fp16 scores -> bf16 P
    softmax_rows<<<MTOT, 256, 0, stream>>>(S);
    // feat = P @ v   (M=16384, N=512, K=2048; B = vt + batch*2048, batch=m0>>11)
    gemm8<128, 0, 0, 0><<<dim3(64, 4, 1), 512, 0, stream>>>(
        S, N_, 0, vt, MTOT, 0, nullptr, feat, A_, 0, 2048, 2048);
    // lin = feat @ Wo^T + bo   (M=16384, N=512, K=512) fp32
    gemm8<128, 1, 1, 0><<<dim3(64, 4, 1), 512, 0, stream>>>(
        feat, 512, 0, wob, 512, 0, bo, lin, 512, 0, 512, 0);

    bn_stats<<<2048, 256, 0, stream>>>(lin, stats);
    bn_relu_add<<<8192, 256, 0, stream>>>(lin, x, gamma, beta, stats, out);
}